// Round 6
// baseline (841.093 us; speedup 1.0000x reference)
//
#include <hip/hip_runtime.h>

// R5b: software-pipelined regions + rcp-fused activations (R5 with the
// intrinsic-name fix: 16x16x16 f16 MFMA is __builtin_amdgcn_mfma_f32_16x16x16f16).
// vs R4 (731us, VALU 51% busy of which ~75% trans, MFMA idle during act):
// (1) loop over barrier regions [mfma1(s); mfma0(s+1); act1(s); act0(s+1)]:
//     mfma0(s+1) depends only on h0(s) (in LDS at region entry), so ALL 56
//     MFMAs issue before the act VALU and drain underneath it; h0 A-frags
//     shared between the two matmuls. Still 1 barrier per encoder step.
// (2) activations algebraically rcp-fused: 7 trans/elem instead of 10.
// (3) x-contribution via 16x16x16 MFMA (K=16 exact) - no zeroed half-K path.

typedef _Float16 half_t;
typedef _Float16 half8 __attribute__((ext_vector_type(8)));
typedef _Float16 half4 __attribute__((ext_vector_type(4)));
typedef float f32x4 __attribute__((ext_vector_type(4)));

#define SEQ 100
#define FUT 30
#define TOT (SEQ + FUT)
#define NIN 15
#define MB  16
#define L2E 1.44269504f

#define MFMA32(A, B, C) __builtin_amdgcn_mfma_f32_16x16x32_f16((A), (B), (C), 0, 0, 0)
#define MFMA16(A, B, C) __builtin_amdgcn_mfma_f32_16x16x16f16((A), (B), (C), 0, 0, 0)

// ---- prep: fp16 repack, gate scales folded (i,f,o: -log2e ; cell g: +2log2e).
// n' = 64*wave + 16*gate + unit%16, unit j = 16*wave + (n&15), row = g*128 + j.
// ws halfword layout:
//   [0,      65536)  WH0[n*128+k]
//   [65536, 131072)  WI1[n*128+k]
//   [131072,196608)  WH1[n*128+k]
//   [196608,204800)  WX [n*16+k]   (k>=15 zero)
//   [204800,206848)  BV: 1024 f32 = scaled (b_ih+b_hh), layer0 then layer1
__global__ void prep_kernel(const float* __restrict__ w_ih0, const float* __restrict__ w_hh0,
                            const float* __restrict__ b_ih0, const float* __restrict__ b_hh0,
                            const float* __restrict__ w_ih1, const float* __restrict__ w_hh1,
                            const float* __restrict__ b_ih1, const float* __restrict__ b_hh1,
                            half_t* __restrict__ wsh)
{
  int idx = blockIdx.x * 256 + threadIdx.x;
  if (idx < 196608) {
    int seg = idx >> 16;
    int r   = idx & 65535;
    int n   = r >> 7, k = r & 127;
    int g   = (n >> 4) & 3;
    int row = g * 128 + ((n >> 6) << 4) + (n & 15);
    float sc = (g == 2) ? (2.0f * L2E) : (-L2E);
    const float* src = (seg == 0) ? w_hh0 : ((seg == 1) ? w_ih1 : w_hh1);
    wsh[idx] = (half_t)(src[row * 128 + k] * sc);
  } else if (idx < 204800) {
    int r   = idx - 196608;
    int n   = r >> 4, k = r & 15;
    int g   = (n >> 4) & 3;
    int row = g * 128 + ((n >> 6) << 4) + (n & 15);
    float sc = (g == 2) ? (2.0f * L2E) : (-L2E);
    wsh[idx] = (half_t)((k < NIN) ? (w_ih0[row * NIN + k] * sc) : 0.0f);
  } else if (idx < 205824) {
    int r     = idx - 204800;
    float* bv = (float*)(wsh + 204800);
    int which = r >> 9, n = r & 511;
    int g     = (n >> 4) & 3;
    int row   = g * 128 + ((n >> 6) << 4) + (n & 15);
    float sc  = (g == 2) ? (2.0f * L2E) : (-L2E);
    bv[r] = ((which == 0) ? (b_ih0[row] + b_hh0[row]) : (b_ih1[row] + b_hh1[row])) * sc;
  }
}

__global__ __launch_bounds__(512, 2)
void lstm_kernel(const float* __restrict__ x,
                 const half_t* __restrict__ wsh,
                 const float* __restrict__ fcw,
                 const float* __restrict__ fcb,
                 float* __restrict__ out)
{
  // XOR-swizzled h tiles: (row m, col k) -> m*128 + (((k>>3) ^ (m&7))<<3) + (k&7)
  __shared__ __align__(16) half_t sx[SEQ * MB * 16];  // 51,200 B
  __shared__ __align__(16) half_t sh0[2][MB * 128];   // 8,192 B
  __shared__ __align__(16) half_t sh1[2][MB * 128];   // 8,192 B
  __shared__ __align__(16) half_t swx[512 * 16];      // 16,384 B
  __shared__ __align__(16) half_t sdec[MB * 16];      // 512 B
  __shared__ __align__(16) float  sbias[1024];        // 4,096 B
  __shared__ __align__(16) float  sfc[258];

  const half_t* WH0 = wsh;
  const half_t* WI1 = wsh + 65536;
  const half_t* WH1 = wsh + 131072;
  const half_t* WX  = wsh + 196608;
  const float*  BV  = (const float*)(wsh + 204800);

  const int tid   = threadIdx.x;
  const int wave  = tid >> 6;
  const int lane  = tid & 63;
  const int l16   = lane & 15;
  const int quad  = lane >> 4;
  const int nb    = wave * 64;
  const int bbase = blockIdx.x * MB;

  // ---- persistent B-fragments: recurrent weights (192 VGPRs) ----
  half8 wh0[4][4], wi1[4][4], wh1[4][4];  // [kt][g]
  #pragma unroll
  for (int kt = 0; kt < 4; ++kt) {
    #pragma unroll
    for (int g = 0; g < 4; ++g) {
      int n = nb + g * 16 + l16;
      int k = kt * 32 + quad * 8;
      wh0[kt][g] = *(const half8*)&WH0[n * 128 + k];
      wi1[kt][g] = *(const half8*)&WI1[n * 128 + k];
      wh1[kt][g] = *(const half8*)&WH1[n * 128 + k];
    }
  }

  // ---- one-time LDS staging ----
  for (int it = tid; it < MB * SEQ * NIN; it += 512) {
    int b = it / (SEQ * NIN); int r = it - b * (SEQ * NIN);
    int s = r / NIN;          int i = r - s * NIN;
    sx[(s * MB + b) * 16 + i] = (half_t)x[(size_t)(bbase + b) * (SEQ * NIN) + r];
  }
  for (int it = tid; it < SEQ * MB; it += 512) sx[it * 16 + 15] = (half_t)0;
  for (int it = tid; it < 8192; it += 512)     swx[it] = WX[it];
  for (int it = tid; it < 1024; it += 512)     sbias[it] = BV[it];
  if (tid < 256) sfc[tid] = fcw[tid];
  if (tid < 2)   sfc[256 + tid] = fcb[tid];
  if (tid < 256) {
    int b = tid >> 4, i = tid & 15;
    sdec[tid] = (i < NIN) ? (half_t)x[(size_t)(bbase + b) * (SEQ * NIN) + 99 * NIN + i]
                          : (half_t)0;
  }
  for (int it = tid; it < MB * 128; it += 512) {
    sh0[0][it] = (half_t)0; sh0[1][it] = (half_t)0;
    sh1[0][it] = (half_t)0; sh1[1][it] = (half_t)0;
  }
  __syncthreads();

  float c0[4] = {0.f, 0.f, 0.f, 0.f};
  float c1[4] = {0.f, 0.f, 0.f, 0.f};
  const int chunk = wave * 2 + (l16 >> 3);

  // fused activation: acc gates pre-scaled (i,f,o by -log2e; g by +2log2e).
  // c' = [c*(1+A)(1+B) + (B-1)(1+C)] / [(1+A)(1+B)(1+C)]
  // h  = (E-1) / [(1+D)(1+E)],  E = 2^(2*log2e*c')
  #define ACT_STORE(ACC, CS, DST)                                              \
    _Pragma("unroll")                                                          \
    for (int r = 0; r < 4; ++r) {                                              \
      float A  = __builtin_amdgcn_exp2f((ACC)[0][r]);                          \
      float C  = __builtin_amdgcn_exp2f((ACC)[1][r]);                          \
      float B  = __builtin_amdgcn_exp2f((ACC)[2][r]);                          \
      float D  = __builtin_amdgcn_exp2f((ACC)[3][r]);                          \
      float oA = 1.f + A, oB = 1.f + B, oC = 1.f + C, oD = 1.f + D;            \
      float P  = oA * oB;                                                      \
      float t  = (B - 1.f) * oC;                                               \
      float nm = fmaf((CS)[r], P, t);                                          \
      float rc = __builtin_amdgcn_rcpf(P * oC);                                \
      float cn = nm * rc;                                                      \
      (CS)[r] = cn;                                                            \
      float E  = __builtin_amdgcn_exp2f(2.0f * L2E * cn);                      \
      float h  = (E - 1.f) * __builtin_amdgcn_rcpf(oD * (1.f + E));            \
      int   m  = quad * 4 + r;                                                 \
      (DST)[m * 128 + ((chunk ^ (m & 7)) << 3) + (l16 & 7)] = (half_t)h;       \
    }

  // ---- preamble: P0(0) = layer0 step 0 (h0 = 0 -> x-part only) ----
  {
    f32x4 acc0[4];
    #pragma unroll
    for (int g = 0; g < 4; ++g) {
      float b = sbias[nb + g * 16 + l16];
      acc0[g] = (f32x4){b, b, b, b};
    }
    half4 ax = *(const half4*)&sx[l16 * 16 + quad * 4];
    #pragma unroll
    for (int g = 0; g < 4; ++g) {
      half4 bx = *(const half4*)&swx[(nb + g * 16 + l16) * 16 + quad * 4];
      acc0[g] = MFMA16(ax, bx, acc0[g]);
    }
    ACT_STORE(acc0, c0, sh0[1])
  }
  __syncthreads();

  int cur = 0;
  for (int s = 0; s < TOT - 1; ++s) {
    const int nxt = cur ^ 1;

    // ---- all MFMAs first: acc1 = gates1(s), acc0 = gates0(s+1) h-part ----
    f32x4 acc1[4], acc0[4];
    #pragma unroll
    for (int g = 0; g < 4; ++g) {
      float b1v = sbias[512 + nb + g * 16 + l16];
      float b0v = sbias[nb + g * 16 + l16];
      acc1[g] = (f32x4){b1v, b1v, b1v, b1v};
      acc0[g] = (f32x4){b0v, b0v, b0v, b0v};
    }
    #pragma unroll
    for (int kt = 0; kt < 4; ++kt) {
      int c = kt * 4 + quad;
      int sw = ((c ^ (l16 & 7)) << 3);
      half8 a0 = *(const half8*)&sh0[nxt][l16 * 128 + sw];   // h0(s)
      #pragma unroll
      for (int g = 0; g < 4; ++g) acc1[g] = MFMA32(a0, wi1[kt][g], acc1[g]);
      #pragma unroll
      for (int g = 0; g < 4; ++g) acc0[g] = MFMA32(a0, wh0[kt][g], acc0[g]);
      half8 a1 = *(const half8*)&sh1[cur][l16 * 128 + sw];   // h1(s-1)
      #pragma unroll
      for (int g = 0; g < 4; ++g) acc1[g] = MFMA32(a1, wh1[kt][g], acc1[g]);
    }
    if (s < SEQ) {  // x(s+1) available now (sx, or initial sdec at s=99)
      const half_t* xrow = (s + 1 < SEQ) ? &sx[((s + 1) * MB + l16) * 16]
                                         : &sdec[l16 * 16];
      half4 ax = *(const half4*)&xrow[quad * 4];
      #pragma unroll
      for (int g = 0; g < 4; ++g) {
        half4 bx = *(const half4*)&swx[(nb + g * 16 + l16) * 16 + quad * 4];
        acc0[g] = MFMA16(ax, bx, acc0[g]);
      }
    }

    // ---- act1(s) -> sh1[nxt]; MFMAs drain underneath ----
    ACT_STORE(acc1, c1, sh1[nxt])

    // ---- decoder: FC(s) then late x-part of acc0 ----
    if (s >= SEQ) {
      __syncthreads();  // B2: h1(s) visible
      if (tid < 256) {
        int b   = wave * 4 + (lane >> 4);
        int o   = (lane >> 3) & 1;
        int seg = lane & 7;
        float p = 0.f;
        #pragma unroll
        for (int cc = 0; cc < 2; ++cc) {
          int c = seg * 2 + cc;
          half8 hv = *(const half8*)&sh1[nxt][b * 128 + ((c ^ (b & 7)) << 3)];
          f32x4 w0 = *(const f32x4*)&sfc[o * 128 + c * 8];
          f32x4 w1 = *(const f32x4*)&sfc[o * 128 + c * 8 + 4];
          #pragma unroll
          for (int u = 0; u < 4; ++u) p = fmaf((float)hv[u], w0[u], p);
          #pragma unroll
          for (int u = 0; u < 4; ++u) p = fmaf((float)hv[4 + u], w1[u], p);
        }
        p += __shfl_down(p, 4);
        p += __shfl_down(p, 2);
        p += __shfl_down(p, 1);
        if (seg == 0) {
          p += sfc[256 + o];
          out[(size_t)(bbase + b) * (FUT * 2) + (s - SEQ) * 2 + o] = p;
          sdec[b * 16 + o] = (half_t)p;
        }
      }
      __syncthreads();  // B3: sdec(s+1) visible
      half4 ax = *(const half4*)&sdec[l16 * 16 + quad * 4];
      #pragma unroll
      for (int g = 0; g < 4; ++g) {
        half4 bx = *(const half4*)&swx[(nb + g * 16 + l16) * 16 + quad * 4];
        acc0[g] = MFMA16(ax, bx, acc0[g]);
      }
    }

    // ---- act0(s+1) -> sh0[cur] ----
    ACT_STORE(acc0, c0, sh0[cur])
    __syncthreads();  // B1
    cur = nxt;
  }

  // ---- epilogue: layer1 step 129 + final FC ----
  {
    const int nxt = cur ^ 1;
    f32x4 acc1[4];
    #pragma unroll
    for (int g = 0; g < 4; ++g) {
      float b = sbias[512 + nb + g * 16 + l16];
      acc1[g] = (f32x4){b, b, b, b};
    }
    #pragma unroll
    for (int kt = 0; kt < 4; ++kt) {
      int c = kt * 4 + quad;
      int sw = ((c ^ (l16 & 7)) << 3);
      half8 a0 = *(const half8*)&sh0[nxt][l16 * 128 + sw];
      #pragma unroll
      for (int g = 0; g < 4; ++g) acc1[g] = MFMA32(a0, wi1[kt][g], acc1[g]);
      half8 a1 = *(const half8*)&sh1[cur][l16 * 128 + sw];
      #pragma unroll
      for (int g = 0; g < 4; ++g) acc1[g] = MFMA32(a1, wh1[kt][g], acc1[g]);
    }
    ACT_STORE(acc1, c1, sh1[nxt])
    __syncthreads();
    if (tid < 256) {
      int b   = wave * 4 + (lane >> 4);
      int o   = (lane >> 3) & 1;
      int seg = lane & 7;
      float p = 0.f;
      #pragma unroll
      for (int cc = 0; cc < 2; ++cc) {
        int c = seg * 2 + cc;
        half8 hv = *(const half8*)&sh1[nxt][b * 128 + ((c ^ (b & 7)) << 3)];
        f32x4 w0 = *(const f32x4*)&sfc[o * 128 + c * 8];
        f32x4 w1 = *(const f32x4*)&sfc[o * 128 + c * 8 + 4];
        #pragma unroll
        for (int u = 0; u < 4; ++u) p = fmaf((float)hv[u], w0[u], p);
        #pragma unroll
        for (int u = 0; u < 4; ++u) p = fmaf((float)hv[4 + u], w1[u], p);
      }
      p += __shfl_down(p, 4);
      p += __shfl_down(p, 2);
      p += __shfl_down(p, 1);
      if (seg == 0) {
        p += sfc[256 + o];
        out[(size_t)(bbase + b) * (FUT * 2) + (FUT - 1) * 2 + o] = p;
      }
    }
  }
}

extern "C" void kernel_launch(void* const* d_in, const int* in_sizes, int n_in,
                              void* d_out, int out_size, void* d_ws, size_t ws_size,
                              hipStream_t stream)
{
  (void)in_sizes; (void)n_in; (void)out_size; (void)ws_size;
  const float* x     = (const float*)d_in[0];
  const float* w_ih0 = (const float*)d_in[1];
  const float* w_hh0 = (const float*)d_in[2];
  const float* b_ih0 = (const float*)d_in[3];
  const float* b_hh0 = (const float*)d_in[4];
  const float* w_ih1 = (const float*)d_in[5];
  const float* w_hh1 = (const float*)d_in[6];
  const float* b_ih1 = (const float*)d_in[7];
  const float* b_hh1 = (const float*)d_in[8];
  const float* fcw   = (const float*)d_in[9];
  const float* fcb   = (const float*)d_in[10];
  float*  out = (float*)d_out;
  half_t* wsh = (half_t*)d_ws;

  prep_kernel<<<(205824 + 255) / 256, 256, 0, stream>>>(
      w_ih0, w_hh0, b_ih0, b_hh0, w_ih1, w_hh1, b_ih1, b_hh1, wsh);
  lstm_kernel<<<8192 / MB, 512, 0, stream>>>(x, wsh, fcw, fcb, out);
}

// Round 7
// 634.595 us; speedup vs baseline: 1.3254x; 1.3254x over previous
//
#include <hip/hip_runtime.h>

// R7: R4 structure (known spill-free, 731us) + the two register-neutral wins
// from R5b: (1) rcp-fused activations, 7 trans/elem instead of 10 (numerics
// HW-verified in R6: absmax unchanged 4.88e-4); (2) x-contribution via K=16
// MFMA (__builtin_amdgcn_mfma_f32_16x16x16f16) - no masked half-K path.
// NO dual-accumulator pipelining: R5b proved acc0+acc1 (32 regs) on top of
// 192 weight regs spills (WRITE_SIZE 11->28.6MB) and regresses. One
// weight-resident 8-wave block per CU is structural (weights ~412KB of RF);
// phases stay barrier-locked: wall ~= MFMA phase + act phase.

typedef _Float16 half_t;
typedef _Float16 half8 __attribute__((ext_vector_type(8)));
typedef _Float16 half4 __attribute__((ext_vector_type(4)));
typedef float f32x4 __attribute__((ext_vector_type(4)));

#define SEQ 100
#define FUT 30
#define TOT (SEQ + FUT)
#define NIN 15
#define MB  16
#define L2E 1.44269504f

#define MFMA32(A, B, C) __builtin_amdgcn_mfma_f32_16x16x32_f16((A), (B), (C), 0, 0, 0)
#define MFMA16(A, B, C) __builtin_amdgcn_mfma_f32_16x16x16f16((A), (B), (C), 0, 0, 0)

// ---- prep: fp16 repack, gate scales folded (i,f,o: -log2e ; cell g: +2log2e).
// n' = 64*wave + 16*gate + unit%16, unit j = 16*wave + (n&15), row = g*128 + j.
// ws halfword layout:
//   [0,      65536)  WH0[n*128+k]
//   [65536, 131072)  WI1[n*128+k]
//   [131072,196608)  WH1[n*128+k]
//   [196608,204800)  WX [n*16+k]   (k>=15 zero)
//   [204800,206848)  BV: 1024 f32 = scaled (b_ih+b_hh), layer0 then layer1
__global__ void prep_kernel(const float* __restrict__ w_ih0, const float* __restrict__ w_hh0,
                            const float* __restrict__ b_ih0, const float* __restrict__ b_hh0,
                            const float* __restrict__ w_ih1, const float* __restrict__ w_hh1,
                            const float* __restrict__ b_ih1, const float* __restrict__ b_hh1,
                            half_t* __restrict__ wsh)
{
  int idx = blockIdx.x * 256 + threadIdx.x;
  if (idx < 196608) {
    int seg = idx >> 16;
    int r   = idx & 65535;
    int n   = r >> 7, k = r & 127;
    int g   = (n >> 4) & 3;
    int row = g * 128 + ((n >> 6) << 4) + (n & 15);
    float sc = (g == 2) ? (2.0f * L2E) : (-L2E);
    const float* src = (seg == 0) ? w_hh0 : ((seg == 1) ? w_ih1 : w_hh1);
    wsh[idx] = (half_t)(src[row * 128 + k] * sc);
  } else if (idx < 204800) {
    int r   = idx - 196608;
    int n   = r >> 4, k = r & 15;
    int g   = (n >> 4) & 3;
    int row = g * 128 + ((n >> 6) << 4) + (n & 15);
    float sc = (g == 2) ? (2.0f * L2E) : (-L2E);
    wsh[idx] = (half_t)((k < NIN) ? (w_ih0[row * NIN + k] * sc) : 0.0f);
  } else if (idx < 205824) {
    int r     = idx - 204800;
    float* bv = (float*)(wsh + 204800);
    int which = r >> 9, n = r & 511;
    int g     = (n >> 4) & 3;
    int row   = g * 128 + ((n >> 6) << 4) + (n & 15);
    float sc  = (g == 2) ? (2.0f * L2E) : (-L2E);
    bv[r] = ((which == 0) ? (b_ih0[row] + b_hh0[row]) : (b_ih1[row] + b_hh1[row])) * sc;
  }
}

__global__ __launch_bounds__(512, 2)
void lstm_kernel(const float* __restrict__ x,
                 const half_t* __restrict__ wsh,
                 const float* __restrict__ fcw,
                 const float* __restrict__ fcb,
                 float* __restrict__ out)
{
  // XOR-swizzled h tiles: (row m, col k) -> m*128 + (((k>>3) ^ (m&7))<<3) + (k&7)
  __shared__ __align__(16) half_t sx[SEQ * MB * 16];  // 51,200 B
  __shared__ __align__(16) half_t sh0[2][MB * 128];   // 8,192 B
  __shared__ __align__(16) half_t sh1[2][MB * 128];   // 8,192 B
  __shared__ __align__(16) half_t swx[512 * 16];      // 16,384 B
  __shared__ __align__(16) half_t sdec[MB * 16];      // 512 B
  __shared__ __align__(16) float  sbias[1024];        // 4,096 B
  __shared__ __align__(16) float  sfc[258];

  const half_t* WH0 = wsh;
  const half_t* WI1 = wsh + 65536;
  const half_t* WH1 = wsh + 131072;
  const half_t* WX  = wsh + 196608;
  const float*  BV  = (const float*)(wsh + 204800);

  const int tid   = threadIdx.x;
  const int wave  = tid >> 6;
  const int lane  = tid & 63;
  const int l16   = lane & 15;
  const int quad  = lane >> 4;
  const int nb    = wave * 64;
  const int bbase = blockIdx.x * MB;

  // ---- persistent B-fragments: recurrent weights (192 VGPRs) ----
  half8 wh0[4][4], wi1[4][4], wh1[4][4];  // [kt][g]
  #pragma unroll
  for (int kt = 0; kt < 4; ++kt) {
    #pragma unroll
    for (int g = 0; g < 4; ++g) {
      int n = nb + g * 16 + l16;
      int k = kt * 32 + quad * 8;
      wh0[kt][g] = *(const half8*)&WH0[n * 128 + k];
      wi1[kt][g] = *(const half8*)&WI1[n * 128 + k];
      wh1[kt][g] = *(const half8*)&WH1[n * 128 + k];
    }
  }

  // ---- one-time LDS staging ----
  for (int it = tid; it < MB * SEQ * NIN; it += 512) {
    int b = it / (SEQ * NIN); int r = it - b * (SEQ * NIN);
    int s = r / NIN;          int i = r - s * NIN;
    sx[(s * MB + b) * 16 + i] = (half_t)x[(size_t)(bbase + b) * (SEQ * NIN) + r];
  }
  for (int it = tid; it < SEQ * MB; it += 512) sx[it * 16 + 15] = (half_t)0;
  for (int it = tid; it < 8192; it += 512)     swx[it] = WX[it];
  for (int it = tid; it < 1024; it += 512)     sbias[it] = BV[it];
  if (tid < 256) sfc[tid] = fcw[tid];
  if (tid < 2)   sfc[256 + tid] = fcb[tid];
  if (tid < 256) {
    int b = tid >> 4, i = tid & 15;
    sdec[tid] = (i < NIN) ? (half_t)x[(size_t)(bbase + b) * (SEQ * NIN) + 99 * NIN + i]
                          : (half_t)0;
  }
  for (int it = tid; it < MB * 128; it += 512) {
    sh0[0][it] = (half_t)0; sh0[1][it] = (half_t)0;
    sh1[0][it] = (half_t)0; sh1[1][it] = (half_t)0;
  }
  __syncthreads();

  float c0[4] = {0.f, 0.f, 0.f, 0.f};
  float c1[4] = {0.f, 0.f, 0.f, 0.f};
  const int chunk = wave * 2 + (l16 >> 3);

  // fused activation: acc gates pre-scaled (i,f,o by -log2e; g by +2log2e).
  // A=e^-xi  C=e^-xf  B=e^+2xg  D=e^-xo:
  // c' = [c*(1+A)(1+B) + (B-1)(1+C)] / [(1+A)(1+B)(1+C)]
  // h  = (E-1) / [(1+D)(1+E)],  E = 2^(2*log2e*c')
  // 5 exp2 + 2 rcp per element (was 10 trans). HW-verified (R6): absmax 4.88e-4.
  #define ACT_STORE(ACC, CS, DST)                                              \
    _Pragma("unroll")                                                          \
    for (int r = 0; r < 4; ++r) {                                              \
      float A  = __builtin_amdgcn_exp2f((ACC)[0][r]);                          \
      float C  = __builtin_amdgcn_exp2f((ACC)[1][r]);                          \
      float B  = __builtin_amdgcn_exp2f((ACC)[2][r]);                          \
      float D  = __builtin_amdgcn_exp2f((ACC)[3][r]);                          \
      float oA = 1.f + A, oB = 1.f + B, oC = 1.f + C, oD = 1.f + D;            \
      float P  = oA * oB;                                                      \
      float t  = (B - 1.f) * oC;                                               \
      float nm = fmaf((CS)[r], P, t);                                          \
      float rc = __builtin_amdgcn_rcpf(P * oC);                                \
      float cn = nm * rc;                                                      \
      (CS)[r] = cn;                                                            \
      float E  = __builtin_amdgcn_exp2f(2.0f * L2E * cn);                      \
      float h  = (E - 1.f) * __builtin_amdgcn_rcpf(oD * (1.f + E));            \
      int   m  = quad * 4 + r;                                                 \
      (DST)[m * 128 + ((chunk ^ (m & 7)) << 3) + (l16 & 7)] = (half_t)h;       \
    }

  int cur = 0;
  for (int s = 0; s < TOT; ++s) {
    const int nxt = cur ^ 1;
    const half_t* xsrc = (s < SEQ) ? &sx[s * MB * 16] : sdec;

    // ================= P0: layer 0 MFMA + act0 =================
    {
      f32x4 acc[4];
      #pragma unroll
      for (int g = 0; g < 4; ++g) {
        float b = sbias[nb + g * 16 + l16];
        acc[g] = (f32x4){b, b, b, b};
      }
      #pragma unroll
      for (int kt = 0; kt < 4; ++kt) {
        int c = kt * 4 + quad;
        half8 ah = *(const half8*)&sh0[cur][l16 * 128 + ((c ^ (l16 & 7)) << 3)];
        #pragma unroll
        for (int g = 0; g < 4; ++g) acc[g] = MFMA32(ah, wh0[kt][g], acc[g]);
      }
      // x contribution: exact K=16 MFMA (cols >= 15 of W zero-padded)
      half4 ax = *(const half4*)&xsrc[l16 * 16 + quad * 4];
      #pragma unroll
      for (int g = 0; g < 4; ++g) {
        half4 bx = *(const half4*)&swx[(nb + g * 16 + l16) * 16 + quad * 4];
        acc[g] = MFMA16(ax, bx, acc[g]);
      }
      ACT_STORE(acc, c0, sh0[nxt])
    }
    __syncthreads();  // B1 (the only encoder barrier)

    // ================= P1: layer 1 MFMA + act1 =================
    {
      f32x4 acc[4];
      #pragma unroll
      for (int g = 0; g < 4; ++g) {
        float b = sbias[512 + nb + g * 16 + l16];
        acc[g] = (f32x4){b, b, b, b};
      }
      #pragma unroll
      for (int kt = 0; kt < 4; ++kt) {
        int c = kt * 4 + quad;
        half8 ah = *(const half8*)&sh0[nxt][l16 * 128 + ((c ^ (l16 & 7)) << 3)];
        #pragma unroll
        for (int g = 0; g < 4; ++g) acc[g] = MFMA32(ah, wi1[kt][g], acc[g]);
      }
      #pragma unroll
      for (int kt = 0; kt < 4; ++kt) {
        int c = kt * 4 + quad;
        half8 ah = *(const half8*)&sh1[cur][l16 * 128 + ((c ^ (l16 & 7)) << 3)];
        #pragma unroll
        for (int g = 0; g < 4; ++g) acc[g] = MFMA32(ah, wh1[kt][g], acc[g]);
      }
      ACT_STORE(acc, c1, sh1[nxt])
    }

    // ================= decoder: FC + feedback =================
    if (s >= SEQ) {
      __syncthreads();  // B2d: h1_new visible
      if (tid < 256) {
        int b   = wave * 4 + (lane >> 4);
        int o   = (lane >> 3) & 1;
        int seg = lane & 7;
        float p = 0.f;
        #pragma unroll
        for (int cc = 0; cc < 2; ++cc) {
          int c = seg * 2 + cc;
          half8 hv = *(const half8*)&sh1[nxt][b * 128 + ((c ^ (b & 7)) << 3)];
          f32x4 w0 = *(const f32x4*)&sfc[o * 128 + c * 8];
          f32x4 w1 = *(const f32x4*)&sfc[o * 128 + c * 8 + 4];
          #pragma unroll
          for (int u = 0; u < 4; ++u) p = fmaf((float)hv[u], w0[u], p);
          #pragma unroll
          for (int u = 0; u < 4; ++u) p = fmaf((float)hv[4 + u], w1[u], p);
        }
        p += __shfl_down(p, 4);
        p += __shfl_down(p, 2);
        p += __shfl_down(p, 1);
        if (seg == 0) {
          p += sfc[256 + o];
          out[(size_t)(bbase + b) * (FUT * 2) + (s - SEQ) * 2 + o] = p;
          sdec[b * 16 + o] = (half_t)p;   // feed back into features 0:2
        }
      }
      __syncthreads();  // B3d: sdec feedback visible
    }

    cur = nxt;
  }
}

extern "C" void kernel_launch(void* const* d_in, const int* in_sizes, int n_in,
                              void* d_out, int out_size, void* d_ws, size_t ws_size,
                              hipStream_t stream)
{
  (void)in_sizes; (void)n_in; (void)out_size; (void)ws_size;
  const float* x     = (const float*)d_in[0];
  const float* w_ih0 = (const float*)d_in[1];
  const float* w_hh0 = (const float*)d_in[2];
  const float* b_ih0 = (const float*)d_in[3];
  const float* b_hh0 = (const float*)d_in[4];
  const float* w_ih1 = (const float*)d_in[5];
  const float* w_hh1 = (const float*)d_in[6];
  const float* b_ih1 = (const float*)d_in[7];
  const float* b_hh1 = (const float*)d_in[8];
  const float* fcw   = (const float*)d_in[9];
  const float* fcb   = (const float*)d_in[10];
  float*  out = (float*)d_out;
  half_t* wsh = (half_t*)d_ws;

  prep_kernel<<<(205824 + 255) / 256, 256, 0, stream>>>(
      w_ih0, w_hh0, b_ih0, b_hh0, w_ih1, w_hh1, b_ih1, b_hh1, wsh);
  lstm_kernel<<<8192 / MB, 512, 0, stream>>>(x, wsh, fcw, fcb, out);
}